// Round 2
// baseline (23959.055 us; speedup 1.0000x reference)
//
#include <hip/hip_runtime.h>
#include <stdint.h>

// ---------------------------------------------------------------------------
// LEM-style noisy RNN. T=128 outer x DIV=10 inner sequential steps, B=256, H=256.
// Phases: prep (fold W_ic=W_i@W_c, pack weights to MFMA-frag order) ->
//         per chunk: [threefry noise gen (partitionable) -> S GEMM -> pack input ->
//                     recurrence (16 WG x 16 rows) -> output GEMM]
// ---------------------------------------------------------------------------

typedef __attribute__((ext_vector_type(8))) short bf16x8_t;
typedef __attribute__((ext_vector_type(4))) float f32x4_t;
typedef unsigned short u16;

#define R_LDS_BYTES 123136

__device__ __forceinline__ float bf2f(u16 b) {
  union { uint32_t u; float f; } v; v.u = ((uint32_t)b) << 16; return v.f;
}
__device__ __forceinline__ u16 f2bf(float f) {
  union { float f; uint32_t u; } v; v.f = f;
  uint32_t x = v.u;
  return (u16)((x + 0x7FFFu + ((x >> 16) & 1u)) >> 16);   // RNE
}
__device__ __forceinline__ f32x4_t mfma16(bf16x8_t a, bf16x8_t b, f32x4_t c) {
  return __builtin_amdgcn_mfma_f32_16x16x32_bf16(a, b, c, 0, 0, 0);
}
__device__ __forceinline__ float sigm(float x) { return 1.0f / (1.0f + __expf(-x)); }
__device__ __forceinline__ float tanh_f(float x) {
  float t = __expf(-2.0f * fabsf(x));
  float r = (1.0f - t) / (1.0f + t);
  return x < 0.0f ? -r : r;
}

// MFMA 16x16x32 bf16 fragment K-position for lane l, elem e (blocked: 4 + 4 @ +16)
__device__ __forceinline__ int fragK(int l, int e) {
  return ((l >> 4) << 2) + (e & 3) + ((e >> 2) << 4);
}
// elem slot within A-frag set [kk][64][8] for activation (row m, col k)
__device__ __forceinline__ int actSlot(int m, int k) {
  int kk = k >> 5; int kl = k & 31;
  int l = (((kl & 15) >> 2) << 4) | (m & 15);
  int e = (kl & 3) | (((kl >> 4) & 1) << 2);
  return ((kk << 6) + l) * 8 + e;
}

// ---- JAX threefry2x32 (20 rounds) ----
__device__ __forceinline__ void threefry(uint32_t k0, uint32_t k1, uint32_t x0, uint32_t x1,
                                         uint32_t* o0, uint32_t* o1) {
  uint32_t ks2 = k0 ^ k1 ^ 0x1BD11BDAu;
  x0 += k0; x1 += k1;
#define TFR(rot) { x0 += x1; x1 = (x1 << rot) | (x1 >> (32 - rot)); x1 ^= x0; }
  TFR(13) TFR(15) TFR(26) TFR(6)   x0 += k1;  x1 += ks2 + 1u;
  TFR(17) TFR(29) TFR(16) TFR(24)  x0 += ks2; x1 += k0 + 2u;
  TFR(13) TFR(15) TFR(26) TFR(6)   x0 += k0;  x1 += k1 + 3u;
  TFR(17) TFR(29) TFR(16) TFR(24)  x0 += k1;  x1 += ks2 + 4u;
  TFR(13) TFR(15) TFR(26) TFR(6)   x0 += ks2; x1 += k0 + 5u;
#undef TFR
  *o0 = x0; *o1 = x1;
}

// bits -> N(0,1) exactly like jax.random.normal f32: uniform in (-1,1) then sqrt(2)*erfinv (XLA poly)
__device__ __forceinline__ float bits2normal(uint32_t bits) {
  union { uint32_t u; float f; } cv; cv.u = 0x3F800000u | (bits >> 9);
  float f = cv.f - 1.0f;                       // [0,1)
  float u = fmaf(f, 2.0f, -0.99999994f);       // (maxval-minval) rounds to exactly 2.0f
  u = fmaxf(u, -0.99999994f);
  float w = -log1pf(-u * u);
  float p;
  if (w < 5.0f) {
    w = w - 2.5f;
    p = 2.81022636e-08f;
    p = fmaf(p, w, 3.43273939e-07f);
    p = fmaf(p, w, -3.5233877e-06f);
    p = fmaf(p, w, -4.39150654e-06f);
    p = fmaf(p, w, 0.00021858087f);
    p = fmaf(p, w, -0.00125372503f);
    p = fmaf(p, w, -0.00417768164f);
    p = fmaf(p, w, 0.246640727f);
    p = fmaf(p, w, 1.50140941f);
  } else {
    w = sqrtf(w) - 3.0f;
    p = -0.000200214257f;
    p = fmaf(p, w, 0.000100950558f);
    p = fmaf(p, w, 0.00134934322f);
    p = fmaf(p, w, -0.00367342844f);
    p = fmaf(p, w, 0.00573950773f);
    p = fmaf(p, w, -0.0076224613f);
    p = fmaf(p, w, 0.00943887047f);
    p = fmaf(p, w, 1.00167406f);
    p = fmaf(p, w, 2.83297682f);
  }
  return 1.41421354f * p * u;
}

// ---------------------------------------------------------------------------
// prep: Wic = W_i @ W_c  (1024x256), bip = b_i + W_i @ b_c
__global__ void k_prep(const float* __restrict__ W_i, const float* __restrict__ W_c,
                       const float* __restrict__ b_i, const float* __restrict__ b_c,
                       float* __restrict__ Wic, float* __restrict__ bip) {
  __shared__ float wi[256];
  __shared__ float red[256];
  int o = blockIdx.x; int tid = threadIdx.x;
  wi[tid] = W_i[o * 256 + tid];
  __syncthreads();
  float acc = 0.f;
  for (int j = 0; j < 256; ++j) acc = fmaf(wi[j], W_c[j * 256 + tid], acc);
  Wic[(size_t)o * 256 + tid] = acc;
  red[tid] = wi[tid] * b_c[tid];
  __syncthreads();
  for (int s = 128; s > 0; s >>= 1) { if (tid < s) red[tid] += red[tid + s]; __syncthreads(); }
  if (tid == 0) bip[o] = b_i[o] + red[0];
}

// pack weights (row-major fp32 O x K) into B-fragment order, bf16.
// slot ((to*KK+kk)*64+l)*8+e <-> src[n=16to+(l&15)][k=32kk+fragK(l,e)]
__global__ void k_packw(const float* __restrict__ srcA, int rowsA, const float* __restrict__ srcB,
                        u16* __restrict__ dst, int O, int K) {
  int t = blockIdx.x * blockDim.x + threadIdx.x;
  int KK = K >> 5;
  int total = (O >> 4) * KK * 64;
  if (t >= total) return;
  int l = t & 63; int kk = (t >> 6) % KK; int to = t / (64 * KK);
  int n = (to << 4) | (l & 15);
  int kb = (kk << 5) + ((l >> 4) << 2);
  const float* src = (n < rowsA) ? (srcA + (size_t)n * K) : (srcB + (size_t)(n - rowsA) * K);
  u16 out[8];
#pragma unroll
  for (int e = 0; e < 8; ++e) out[e] = f2bf(src[kb + (e & 3) + ((e >> 2) << 4)]);
  *reinterpret_cast<uint4*>(dst + (size_t)t * 8) = *reinterpret_cast<const uint4*>(out);
}

// pack input chunk into A-fragment order: slot ((tl*16+mt)*8+kk)*512 + l*8 + e
__global__ void k_packa(const float* __restrict__ inp, int t0, int Tcc, u16* __restrict__ dst) {
  int t = blockIdx.x * blockDim.x + threadIdx.x;
  int total = Tcc * 16 * 8 * 64;
  if (t >= total) return;
  int l = t & 63; int kk = (t >> 6) & 7; int mt = (t >> 9) & 15; int tl = t >> 13;
  int b = (mt << 4) | (l & 15);
  int kb = (kk << 5) + ((l >> 4) << 2);
  const float* src = inp + ((size_t)(t0 + tl) * 256 + b) * 256;
  u16 out[8];
#pragma unroll
  for (int e = 0; e < 8; ++e) out[e] = f2bf(src[kb + (e & 3) + ((e >> 2) << 4)]);
  *reinterpret_cast<uint4*>(dst + (size_t)t * 8) = *reinterpret_cast<const uint4*>(out);
}

// noise gen, JAX threefry PARTITIONABLE semantics (default since jax 0.4.30):
// bits[i] = o0 ^ o1, (o0,o1) = threefry(fold_key, hi32(i)=0, lo32(i)), i = b*512 + c.
// One thread per element; writes bf16 normals directly in A-fragment-packed order.
__global__ void k_gen(u16* __restrict__ Apack, int gstep0) {
  int sl = blockIdx.x >> 7;
  int tb = (blockIdx.x & 127) * 1024 + threadIdx.x;   // [0, 131072)
  __shared__ uint32_t kf[2];
  if (threadIdx.x == 0) {
    uint32_t o0, o1;
    threefry(0u, 1234u, 0u, (uint32_t)(gstep0 + sl), &o0, &o1);  // fold_in(key(1234), t*10+d)
    kf[0] = o0; kf[1] = o1;
  }
  __syncthreads();
  int e = tb & 7; int l = (tb >> 3) & 63; int kk = (tb >> 9) & 15; int mt = tb >> 13; // mt<16
  int b = (mt << 4) | (l & 15);                         // [0,256)
  int c = (kk << 5) + fragK(l, e);                      // [0,512)
  uint32_t i = (uint32_t)(b * 512 + c);
  uint32_t o0, o1;
  threefry(kf[0], kf[1], 0u, i, &o0, &o1);
  Apack[(size_t)sl * 131072 + tb] = f2bf(bits2normal(o0 ^ o1));
}

// S = tanh(noise @ Ws^T + b_s), bf16 row-major [step][b][512]
__global__ __launch_bounds__(512) void k_sgemm(const u16* __restrict__ Apack,
                                               const u16* __restrict__ Wspack,
                                               const float* __restrict__ b_s,
                                               u16* __restrict__ S) {
  int sl = blockIdx.x; int nq = blockIdx.y;             // n-quarter
  int l = threadIdx.x & 63; int wv = threadIdx.x >> 6;  // 8 waves
  const u16* Ab = Apack + (size_t)sl * 131072;
#pragma unroll 1
  for (int mtl = 0; mtl < 2; ++mtl) {
    int mt = 2 * wv + mtl;
    bf16x8_t af[16];
#pragma unroll
    for (int kk = 0; kk < 16; ++kk)
      af[kk] = *reinterpret_cast<const bf16x8_t*>(Ab + ((size_t)(mt * 16 + kk) * 64 + l) * 8);
#pragma unroll 1
    for (int ntl = 0; ntl < 8; ++ntl) {
      int nt = nq * 8 + ntl;
      f32x4_t acc = {0.f, 0.f, 0.f, 0.f};
#pragma unroll
      for (int kk = 0; kk < 16; ++kk) {
        bf16x8_t bfr = *reinterpret_cast<const bf16x8_t*>(Wspack + ((size_t)(nt * 16 + kk) * 64 + l) * 8);
        acc = mfma16(af[kk], bfr, acc);
      }
      int n = (nt << 4) | (l & 15);
      float bs = b_s[n];
#pragma unroll
      for (int r = 0; r < 4; ++r) {
        int m = (mt << 4) + ((l >> 4) << 2) + r;
        S[((size_t)sl * 256 + m) * 512 + n] = f2bf(tanh_f(acc[r] + bs));
      }
    }
  }
}

// ---------------------------------------------------------------------------
// Recurrence: 16 WGs x 16 batch rows, 8 waves. Sequential over Tcc*10 steps.
__global__ __launch_bounds__(512, 1) void k_recur(
    const float* __restrict__ dt,
    const u16* __restrict__ Epack, const u16* __restrict__ Wipack, const u16* __restrict__ Wzpack,
    const float* __restrict__ bip, const float* __restrict__ b_i, const float* __restrict__ b_h,
    const float* __restrict__ b_z, const float* __restrict__ W_dt, const float* __restrict__ b_dt,
    const u16* __restrict__ inpPack, const u16* __restrict__ S,
    u16* __restrict__ Ypack, float* __restrict__ ystate, float* __restrict__ zstate,
    int t0, int Tcc)
{
  extern __shared__ char lds_raw[];
  float* G    = (float*)lds_raw;            // [16][1025] fp32 (pad 1025 vs bank conflicts)
  float* Yp   = G + 16 * 1025;              // [16][256] y (post-noise carry)
  float* Z    = Yp + 4096;                  // [16][256] z (post-noise carry)
  u16* ypre   = (u16*)(Z + 4096);           // 4096 bf16, A-frag packed (y pre-noise)
  u16* ypost  = ypre + 4096;                // 4096 bf16, A-frag packed (y post-noise)
  u16* zbf    = ypost + 4096;               // 4096 bf16, A-frag packed (z pre-noise)
  float* sc   = (float*)(zbf + 4096);       // delta[16], sig(tdt1)[16], sig(tdt2)[16]

  const int Wg = blockIdx.x;
  const int tid = threadIdx.x;
  const int l = tid & 63;
  const int wv = tid >> 6;
  const int mB = tid >> 5;                  // elementwise row 0..15
  const int h0 = (tid & 31) * 8;            // elementwise 8-col base

  if (t0 == 0) {
#pragma unroll
    for (int j = 0; j < 8; ++j) {
      int h = h0 + j;
      Yp[mB * 256 + h] = 0.f; Z[mB * 256 + h] = 0.f;
      ypost[actSlot(mB, h)] = 0;
    }
  } else {
#pragma unroll
    for (int j = 0; j < 8; ++j) {
      int h = h0 + j;
      float yv = ystate[(size_t)(Wg * 16 + mB) * 256 + h];
      float zv = zstate[(size_t)(Wg * 16 + mB) * 256 + h];
      Yp[mB * 256 + h] = yv; Z[mB * 256 + h] = zv;
      ypost[actSlot(mB, h)] = f2bf(yv);
    }
  }
  __syncthreads();

  float wdt0 = W_dt[0], wdt1 = W_dt[1], bdt0 = b_dt[0], bdt1 = b_dt[1];

  for (int tl = 0; tl < Tcc; ++tl) {
    int t = t0 + tl;
    if (tid < 16) {
      float dl = dt[(size_t)t * 256 + Wg * 16 + tid] / 10.0f;
      sc[tid] = dl;
      sc[16 + tid] = sigm(fmaf(dl, wdt0, bdt0));   // sigmoid(t_dt1) -> ms_dt_bar (y gate)
      sc[32 + tid] = sigm(fmaf(dl, wdt1, bdt1));   // sigmoid(t_dt2) -> ms_dt (z gate)
    }
    for (int d = 0; d < 10; ++d) {
      int step = tl * 10 + d;
      // ---- Phase A1: ti (1024 outs). d=0: W_i @ inp; d>0: W_ic @ y_pre ----
      {
        bf16x8_t af[8];
        if (d == 0) {
          const u16* ap = inpPack + ((size_t)(tl * 16 + Wg) * 8) * 512 + (size_t)l * 8;
#pragma unroll
          for (int kk = 0; kk < 8; ++kk) af[kk] = *reinterpret_cast<const bf16x8_t*>(ap + kk * 512);
        } else {
#pragma unroll
          for (int kk = 0; kk < 8; ++kk) af[kk] = *reinterpret_cast<const bf16x8_t*>(ypre + (kk * 64 + l) * 8);
        }
        const u16* Bw = (d == 0) ? Wipack : Epack;
        const float* bias = (d == 0) ? b_i : bip;
#pragma unroll 2
        for (int ti_ = 0; ti_ < 8; ++ti_) {
          int to = 8 * wv + ti_;
          f32x4_t acc = {0.f, 0.f, 0.f, 0.f};
          const u16* bp = Bw + ((size_t)to * 8 * 64 + l) * 8;
#pragma unroll
          for (int kk = 0; kk < 8; ++kk) {
            bf16x8_t bfr = *reinterpret_cast<const bf16x8_t*>(bp + kk * 512);
            acc = mfma16(af[kk], bfr, acc);
          }
          int n = (to << 4) | (l & 15);
          float bv = bias[n];
#pragma unroll
          for (int r = 0; r < 4; ++r)
            G[(((l >> 4) << 2) + r) * 1025 + n] = acc[r] + bv;
        }
      }
      __syncthreads();
      // ---- Phase A2: th (768 outs) = W_h @ y_post, accumulate into G ----
      {
        bf16x8_t ag[8];
#pragma unroll
        for (int kk = 0; kk < 8; ++kk) ag[kk] = *reinterpret_cast<const bf16x8_t*>(ypost + (kk * 64 + l) * 8);
#pragma unroll 2
        for (int ti_ = 0; ti_ < 6; ++ti_) {
          int to = 6 * wv + ti_;
          f32x4_t acc = {0.f, 0.f, 0.f, 0.f};
          const u16* bp = Epack + ((size_t)(64 + to) * 8 * 64 + l) * 8;
#pragma unroll
          for (int kk = 0; kk < 8; ++kk) {
            bf16x8_t bfr = *reinterpret_cast<const bf16x8_t*>(bp + kk * 512);
            acc = mfma16(ag[kk], bfr, acc);
          }
          int n = (to << 4) | (l & 15);
          int col = n + (n >= 512 ? 256 : 0);    // h_dt1,h_dt2 align; h_y -> i_y slot
          float bh = b_h[n];
#pragma unroll
          for (int r = 0; r < 4; ++r)
            G[(((l >> 4) << 2) + r) * 1025 + col] += acc[r] + bh;
        }
      }
      __syncthreads();
      // ---- Phase B: z update ----
      {
        float dl = sc[mB]; float s2v = sc[32 + mB];
        const u16* Srow = S + ((size_t)step * 256 + Wg * 16 + mB) * 512;
#pragma unroll
        for (int j = 0; j < 8; ++j) {
          int h = h0 + j;
          float pre2 = G[mB * 1025 + 256 + h];          // i_dt2 + h_dt2
          float iy   = G[mB * 1025 + 768 + h];          // i_y + h_y
          float ms = s2v * sigm(pre2);
          float zo = Z[mB * 256 + h];
          float zn = (1.0f - ms) * zo + ms * tanh_f(iy);
          zbf[actSlot(mB, h)] = f2bf(zn);               // pre-noise z feeds W_z
          float nz = bf2f(Srow[256 + h]);
          Z[mB * 256 + h] = fmaf(nz, dl, zn);           // post-noise carry
        }
      }
      __syncthreads();
      // ---- Phase C/D: u = W_z@z_new + b_z + i_z; y update; noise; frag writeback ----
      {
        bf16x8_t az[8];
#pragma unroll
        for (int kk = 0; kk < 8; ++kk) az[kk] = *reinterpret_cast<const bf16x8_t*>(zbf + (kk * 64 + l) * 8);
        const u16* Sst = S + (size_t)step * 131072 + (size_t)Wg * 8192;
#pragma unroll
        for (int tz_ = 0; tz_ < 2; ++tz_) {
          int tz = 2 * wv + tz_;
          f32x4_t acc = {0.f, 0.f, 0.f, 0.f};
          const u16* bp = Wzpack + ((size_t)tz * 8 * 64 + l) * 8;
#pragma unroll
          for (int kk = 0; kk < 8; ++kk) {
            bf16x8_t bfr = *reinterpret_cast<const bf16x8_t*>(bp + kk * 512);
            acc = mfma16(az[kk], bfr, acc);
          }
          int n = (tz << 4) | (l & 15);
          float bz = b_z[n];
#pragma unroll
          for (int r = 0; r < 4; ++r) {
            int m2 = ((l >> 4) << 2) + r;
            float u = acc[r] + bz + G[m2 * 1025 + 512 + n];          // + i_z
            float msb = sc[16 + m2] * sigm(G[m2 * 1025 + n]);        // sig(tdt1)*sig(i_dt1+h_dt1)
            float yo = Yp[m2 * 256 + n];
            float yn = (1.0f - msb) * yo + msb * tanh_f(u);          // pre-noise y
            float ny = bf2f(Sst[(size_t)m2 * 512 + n]);
            float ypn = fmaf(ny, sc[m2], yn);                        // post-noise y
            Yp[m2 * 256 + n] = ypn;
            int slot = actSlot(m2, n);
            ypre[slot]  = f2bf(yn);
            ypost[slot] = f2bf(ypn);
            if (d == 9)
              Ypack[(size_t)(tl * 16 + Wg) * 4096 + slot] = f2bf(ypn);
          }
        }
      }
      __syncthreads();
    }
  }
#pragma unroll
  for (int j = 0; j < 8; ++j) {
    int h = h0 + j;
    ystate[(size_t)(Wg * 16 + mB) * 256 + h] = Yp[mB * 256 + h];
    zstate[(size_t)(Wg * 16 + mB) * 256 + h] = Z[mB * 256 + h];
  }
}

// out[t] = Y[t] @ W_c^T + b_c
__global__ __launch_bounds__(512) void k_out(const u16* __restrict__ Ypack, const u16* __restrict__ Wcpack,
                                             const float* __restrict__ b_c, float* __restrict__ out, int t0) {
  int tl = blockIdx.x; int mh = blockIdx.y;
  int l = threadIdx.x & 63; int wv = threadIdx.x >> 6;
  int mt = mh * 8 + wv;
  const u16* Ab = Ypack + (size_t)(tl * 16 + mt) * 4096 + (size_t)l * 8;
  bf16x8_t af[8];
#pragma unroll
  for (int kk = 0; kk < 8; ++kk) af[kk] = *reinterpret_cast<const bf16x8_t*>(Ab + kk * 512);
#pragma unroll 1
  for (int nt = 0; nt < 16; ++nt) {
    f32x4_t acc = {0.f, 0.f, 0.f, 0.f};
    const u16* bp = Wcpack + ((size_t)nt * 8 * 64 + l) * 8;
#pragma unroll
    for (int kk = 0; kk < 8; ++kk) {
      bf16x8_t bfr = *reinterpret_cast<const bf16x8_t*>(bp + kk * 512);
      acc = mfma16(af[kk], bfr, acc);
    }
    int n = (nt << 4) | (l & 15);
    float bc = b_c[n];
#pragma unroll
    for (int r = 0; r < 4; ++r) {
      int m = (mt << 4) + ((l >> 4) << 2) + r;
      out[((size_t)(t0 + tl) * 256 + m) * 256 + n] = acc[r] + bc;
    }
  }
}

// ---------------------------------------------------------------------------
extern "C" void kernel_launch(void* const* d_in, const int* in_sizes, int n_in,
                              void* d_out, int out_size, void* d_ws, size_t ws_size,
                              hipStream_t stream) {
  const float* input = (const float*)d_in[0];
  const float* dt    = (const float*)d_in[1];
  const float* W_i   = (const float*)d_in[2];
  const float* b_i   = (const float*)d_in[3];
  const float* W_h   = (const float*)d_in[4];
  const float* b_h   = (const float*)d_in[5];
  const float* W_z   = (const float*)d_in[6];
  const float* b_z   = (const float*)d_in[7];
  const float* W_dt  = (const float*)d_in[8];
  const float* b_dt  = (const float*)d_in[9];
  const float* W_c   = (const float*)d_in[10];
  const float* b_c   = (const float*)d_in[11];
  const float* W_s   = (const float*)d_in[12];
  const float* b_s   = (const float*)d_in[13];
  float* out = (float*)d_out;

  char* ws = (char*)d_ws;
  size_t off = 0;
  auto alloc = [&](size_t bytes) -> char* {
    char* p = ws + off; off = (off + bytes + 255) & ~(size_t)255; return p;
  };
  u16* Epack   = (u16*)alloc((size_t)112 * 8 * 512 * 2);   // [Wic;Wh] 1792x256
  u16* Wipack  = (u16*)alloc((size_t)64 * 8 * 512 * 2);
  u16* Wzpack  = (u16*)alloc((size_t)16 * 8 * 512 * 2);
  u16* Wcpack  = (u16*)alloc((size_t)16 * 8 * 512 * 2);
  u16* Wspack  = (u16*)alloc((size_t)32 * 16 * 512 * 2);
  float* bip   = (float*)alloc(1024 * 4);
  float* Wic   = (float*)alloc((size_t)1024 * 256 * 4);
  float* ystate= (float*)alloc((size_t)256 * 256 * 4);
  float* zstate= (float*)alloc((size_t)256 * 256 * 4);
  size_t fixed = off;
  size_t per_t = (size_t)10 * 131072 * 2 + (size_t)10 * 131072 * 2   // Apack + S
               + (size_t)16 * 8 * 512 * 2 + (size_t)16 * 8 * 512 * 2 // inpPack + Ypack
               + 4 * 256;
  int Tc = 1;
  if (ws_size > fixed + per_t) {
    size_t n = (ws_size - fixed) / per_t;
    Tc = (n > 128) ? 128 : (int)n;
  }
  if (Tc < 1) Tc = 1;
  u16* Apack   = (u16*)alloc((size_t)Tc * 10 * 131072 * 2);
  u16* S       = (u16*)alloc((size_t)Tc * 10 * 131072 * 2);
  u16* inpPack = (u16*)alloc((size_t)Tc * 16 * 8 * 512 * 2);
  u16* Ypack   = (u16*)alloc((size_t)Tc * 16 * 8 * 512 * 2);

  hipFuncSetAttribute((const void*)k_recur, hipFuncAttributeMaxDynamicSharedMemorySize, R_LDS_BYTES);

  k_prep<<<1024, 256, 0, stream>>>(W_i, W_c, b_i, b_c, Wic, bip);
  k_packw<<<(112 * 8 * 64) / 256, 256, 0, stream>>>(Wic, 1024, W_h, Epack, 1792, 256);
  k_packw<<<(64 * 8 * 64) / 256, 256, 0, stream>>>(W_i, 1024, (const float*)nullptr, Wipack, 1024, 256);
  k_packw<<<(16 * 8 * 64) / 256, 256, 0, stream>>>(W_z, 256, (const float*)nullptr, Wzpack, 256, 256);
  k_packw<<<(16 * 8 * 64) / 256, 256, 0, stream>>>(W_c, 256, (const float*)nullptr, Wcpack, 256, 256);
  k_packw<<<(32 * 16 * 64) / 256, 256, 0, stream>>>(W_s, 512, (const float*)nullptr, Wspack, 512, 512);

  for (int t0 = 0; t0 < 128; t0 += Tc) {
    int Tcc = (128 - t0 < Tc) ? (128 - t0) : Tc;
    int nsteps = Tcc * 10;
    k_gen<<<nsteps * 128, 1024, 0, stream>>>(Apack, t0 * 10);
    dim3 g2(nsteps, 4);
    k_sgemm<<<g2, 512, 0, stream>>>(Apack, Wspack, b_s, S);
    int totalA = Tcc * 16 * 8 * 64;
    k_packa<<<(totalA + 255) / 256, 256, 0, stream>>>(input, t0, Tcc, inpPack);
    k_recur<<<16, 512, R_LDS_BYTES, stream>>>(dt, Epack, Wipack, Wzpack, bip, b_i, b_h, b_z,
                                              W_dt, b_dt, inpPack, S, Ypack, ystate, zstate, t0, Tcc);
    dim3 ge(Tcc, 2);
    k_out<<<ge, 512, 0, stream>>>(Ypack, Wcpack, b_c, out, t0);
  }
}

// Round 3
// 17851.672 us; speedup vs baseline: 1.3421x; 1.3421x over previous
//
#include <hip/hip_runtime.h>
#include <stdint.h>

// ---------------------------------------------------------------------------
// LEM-style noisy RNN. T=128 x DIV=10 sequential steps, B=256, H=256.
// k_recur: 16 WGs x 16 batch rows, 8 waves, 3 barriers/step.
//   Phase A: merged ti+th MFMAs (acc-fused) -> G
//   Phase B: z elementwise (carry in regs), zbf frags (swizzled)
//   Phase C: W_z MFMA + y elementwise (carry in regs), y frags (swizzled)
// Noise S pre-permuted into per-consumer layouts; prefetched 16B/thread/step.
// ---------------------------------------------------------------------------

typedef __attribute__((ext_vector_type(8))) short bf16x8_t;
typedef __attribute__((ext_vector_type(4))) float f32x4_t;
typedef unsigned short u16;

#define R_LDS_BYTES 90624

__device__ __forceinline__ float bf2f(u16 b) {
  union { uint32_t u; float f; } v; v.u = ((uint32_t)b) << 16; return v.f;
}
__device__ __forceinline__ u16 f2bf(float f) {
  union { float f; uint32_t u; } v; v.f = f;
  uint32_t x = v.u;
  return (u16)((x + 0x7FFFu + ((x >> 16) & 1u)) >> 16);   // RNE
}
__device__ __forceinline__ f32x4_t mfma16(bf16x8_t a, bf16x8_t b, f32x4_t c) {
  return __builtin_amdgcn_mfma_f32_16x16x32_bf16(a, b, c, 0, 0, 0);
}
__device__ __forceinline__ float sigm(float x) { return 1.0f / (1.0f + __expf(-x)); }
__device__ __forceinline__ float tanh_f(float x) {
  float t = __expf(-2.0f * fabsf(x));
  float r = (1.0f - t) / (1.0f + t);
  return x < 0.0f ? -r : r;
}
// granule swizzle for LDS frag buffers (producer scatter vs consumer b128)
__device__ __forceinline__ int gsw(int g) { return g ^ ((g >> 3) & 7); }

// MFMA 16x16x32 bf16 A-frag K-position for lane l, elem e
__device__ __forceinline__ int fragK(int l, int e) {
  return ((l >> 4) << 2) + (e & 3) + ((e >> 2) << 4);
}

// ---- JAX threefry2x32 (20 rounds) ----
__device__ __forceinline__ void threefry(uint32_t k0, uint32_t k1, uint32_t x0, uint32_t x1,
                                         uint32_t* o0, uint32_t* o1) {
  uint32_t ks2 = k0 ^ k1 ^ 0x1BD11BDAu;
  x0 += k0; x1 += k1;
#define TFR(rot) { x0 += x1; x1 = (x1 << rot) | (x1 >> (32 - rot)); x1 ^= x0; }
  TFR(13) TFR(15) TFR(26) TFR(6)   x0 += k1;  x1 += ks2 + 1u;
  TFR(17) TFR(29) TFR(16) TFR(24)  x0 += ks2; x1 += k0 + 2u;
  TFR(13) TFR(15) TFR(26) TFR(6)   x0 += k0;  x1 += k1 + 3u;
  TFR(17) TFR(29) TFR(16) TFR(24)  x0 += k1;  x1 += ks2 + 4u;
  TFR(13) TFR(15) TFR(26) TFR(6)   x0 += ks2; x1 += k0 + 5u;
#undef TFR
  *o0 = x0; *o1 = x1;
}

// bits -> N(0,1), matches jax.random.normal f32 (XLA erfinv poly)
__device__ __forceinline__ float bits2normal(uint32_t bits) {
  union { uint32_t u; float f; } cv; cv.u = 0x3F800000u | (bits >> 9);
  float f = cv.f - 1.0f;
  float u = fmaf(f, 2.0f, -0.99999994f);
  u = fmaxf(u, -0.99999994f);
  float w = -log1pf(-u * u);
  float p;
  if (w < 5.0f) {
    w = w - 2.5f;
    p = 2.81022636e-08f;
    p = fmaf(p, w, 3.43273939e-07f);
    p = fmaf(p, w, -3.5233877e-06f);
    p = fmaf(p, w, -4.39150654e-06f);
    p = fmaf(p, w, 0.00021858087f);
    p = fmaf(p, w, -0.00125372503f);
    p = fmaf(p, w, -0.00417768164f);
    p = fmaf(p, w, 0.246640727f);
    p = fmaf(p, w, 1.50140941f);
  } else {
    w = sqrtf(w) - 3.0f;
    p = -0.000200214257f;
    p = fmaf(p, w, 0.000100950558f);
    p = fmaf(p, w, 0.00134934322f);
    p = fmaf(p, w, -0.00367342844f);
    p = fmaf(p, w, 0.00573950773f);
    p = fmaf(p, w, -0.0076224613f);
    p = fmaf(p, w, 0.00943887047f);
    p = fmaf(p, w, 1.00167406f);
    p = fmaf(p, w, 2.83297682f);
  }
  return 1.41421354f * p * u;
}

// ---------------------------------------------------------------------------
// prep: Wic = W_i @ W_c  (1024x256), bip = b_i + W_i @ b_c
__global__ void k_prep(const float* __restrict__ W_i, const float* __restrict__ W_c,
                       const float* __restrict__ b_i, const float* __restrict__ b_c,
                       float* __restrict__ Wic, float* __restrict__ bip) {
  __shared__ float wi[256];
  __shared__ float red[256];
  int o = blockIdx.x; int tid = threadIdx.x;
  wi[tid] = W_i[o * 256 + tid];
  __syncthreads();
  float acc = 0.f;
  for (int j = 0; j < 256; ++j) acc = fmaf(wi[j], W_c[j * 256 + tid], acc);
  Wic[(size_t)o * 256 + tid] = acc;
  red[tid] = wi[tid] * b_c[tid];
  __syncthreads();
  for (int s = 128; s > 0; s >>= 1) { if (tid < s) red[tid] += red[tid + s]; __syncthreads(); }
  if (tid == 0) bip[o] = b_i[o] + red[0];
}

// combined biases: bias(c) = base(c) + bh(c), bh = b_h[c] (c<512), b_h[c-256] (c>=768)
__global__ void k_bias(const float* __restrict__ b_i, const float* __restrict__ bip,
                       const float* __restrict__ b_h,
                       float* __restrict__ biasD0, float* __restrict__ biasDn) {
  int c = blockIdx.x * 256 + threadIdx.x;
  float bh = (c < 512) ? b_h[c] : (c >= 768 ? b_h[c - 256] : 0.f);
  biasD0[c] = b_i[c] + bh;
  biasDn[c] = bip[c] + bh;
}

// pack weights (row-major fp32 O x K) into B-fragment order, bf16.
__global__ void k_packw(const float* __restrict__ srcA, int rowsA, const float* __restrict__ srcB,
                        u16* __restrict__ dst, int O, int K) {
  int t = blockIdx.x * blockDim.x + threadIdx.x;
  int KK = K >> 5;
  int total = (O >> 4) * KK * 64;
  if (t >= total) return;
  int l = t & 63; int kk = (t >> 6) % KK; int to = t / (64 * KK);
  int n = (to << 4) | (l & 15);
  int kb = (kk << 5) + ((l >> 4) << 2);
  const float* src = (n < rowsA) ? (srcA + (size_t)n * K) : (srcB + (size_t)(n - rowsA) * K);
  u16 out[8];
#pragma unroll
  for (int e = 0; e < 8; ++e) out[e] = f2bf(src[kb + (e & 3) + ((e >> 2) << 4)]);
  *reinterpret_cast<uint4*>(dst + (size_t)t * 8) = *reinterpret_cast<const uint4*>(out);
}

// pack input chunk into A-fragment order (plain, global)
__global__ void k_packa(const float* __restrict__ inp, int t0, int Tcc, u16* __restrict__ dst) {
  int t = blockIdx.x * blockDim.x + threadIdx.x;
  int total = Tcc * 16 * 8 * 64;
  if (t >= total) return;
  int l = t & 63; int kk = (t >> 6) & 7; int mt = (t >> 9) & 15; int tl = t >> 13;
  int b = (mt << 4) | (l & 15);
  int kb = (kk << 5) + ((l >> 4) << 2);
  const float* src = inp + ((size_t)(t0 + tl) * 256 + b) * 256;
  u16 out[8];
#pragma unroll
  for (int e = 0; e < 8; ++e) out[e] = f2bf(src[kb + (e & 3) + ((e >> 2) << 4)]);
  *reinterpret_cast<uint4*>(dst + (size_t)t * 8) = *reinterpret_cast<const uint4*>(out);
}

// noise gen, JAX threefry partitionable: bits[i] = o0^o1, (o0,o1)=threefry(key, 0, i)
__global__ void k_gen(u16* __restrict__ Apack, int gstep0) {
  int sl = blockIdx.x >> 7;
  int tb = (blockIdx.x & 127) * 1024 + threadIdx.x;   // [0, 131072)
  __shared__ uint32_t kf[2];
  if (threadIdx.x == 0) {
    uint32_t o0, o1;
    threefry(0u, 1234u, 0u, (uint32_t)(gstep0 + sl), &o0, &o1);
    kf[0] = o0; kf[1] = o1;
  }
  __syncthreads();
  int e = tb & 7; int l = (tb >> 3) & 63; int kk = (tb >> 9) & 15; int mt = tb >> 13;
  int b = (mt << 4) | (l & 15);
  int c = (kk << 5) + fragK(l, e);
  uint32_t i = (uint32_t)(b * 512 + c);
  uint32_t o0, o1;
  threefry(kf[0], kf[1], 0u, i, &o0, &o1);
  Apack[(size_t)sl * 131072 + tb] = f2bf(bits2normal(o0 ^ o1));
}

// S = tanh(noise @ Ws^T + b_s). Writes split pre-permuted layouts:
//   Snz (n>=256): [step][Wg][tid(=row*32+h/8)][8]   (phase-B thread order)
//   Sny (n<256):  [step][Wg][tid(=wv*64+l)][8]      (phase-C lane order, e=(tz_<<2)|r)
__global__ __launch_bounds__(512) void k_sgemm(const u16* __restrict__ Apack,
                                               const u16* __restrict__ Wspack,
                                               const float* __restrict__ b_s,
                                               u16* __restrict__ Sny, u16* __restrict__ Snz) {
  int sl = blockIdx.x; int nq = blockIdx.y;
  int l = threadIdx.x & 63; int wv = threadIdx.x >> 6;
  const u16* Ab = Apack + (size_t)sl * 131072;
#pragma unroll 1
  for (int mtl = 0; mtl < 2; ++mtl) {
    int mt = 2 * wv + mtl;
    bf16x8_t af[16];
#pragma unroll
    for (int kk = 0; kk < 16; ++kk)
      af[kk] = *reinterpret_cast<const bf16x8_t*>(Ab + ((size_t)(mt * 16 + kk) * 64 + l) * 8);
#pragma unroll 1
    for (int ntl = 0; ntl < 8; ++ntl) {
      int nt = nq * 8 + ntl;
      f32x4_t acc = {0.f, 0.f, 0.f, 0.f};
#pragma unroll
      for (int kk = 0; kk < 16; ++kk) {
        bf16x8_t bfr = *reinterpret_cast<const bf16x8_t*>(Wspack + ((size_t)(nt * 16 + kk) * 64 + l) * 8);
        acc = mfma16(af[kk], bfr, acc);
      }
      int n = (nt << 4) | (l & 15);
      float bs = b_s[n];
#pragma unroll
      for (int r = 0; r < 4; ++r) {
        int m = (mt << 4) + ((l >> 4) << 2) + r;
        u16 v = f2bf(tanh_f(acc[r] + bs));
        int Wg = m >> 4, row = m & 15;
        if (n >= 256) {
          int h = n - 256;
          Snz[(((size_t)sl * 16 + Wg) * 512 + ((row << 5) | (h >> 3))) * 8 + (h & 7)] = v;
        } else {
          int tz = n >> 4;
          int e = ((tz & 1) << 2) | (row & 3);
          int ll = ((row >> 2) << 4) | (n & 15);
          Sny[(((size_t)sl * 16 + Wg) * 512 + ((tz >> 1) * 64 + ll)) * 8 + e] = v;
        }
      }
    }
  }
}

// ---------------------------------------------------------------------------
__global__ __launch_bounds__(512) void k_recur(
    const float* __restrict__ dt,
    const u16* __restrict__ Epack, const u16* __restrict__ Wipack, const u16* __restrict__ Wzpack,
    const float* __restrict__ biasD0, const float* __restrict__ biasDn,
    const float* __restrict__ b_z, const float* __restrict__ W_dt, const float* __restrict__ b_dt,
    const u16* __restrict__ inpPack, const u16* __restrict__ Sny, const u16* __restrict__ Snz,
    u16* __restrict__ Ypack, float* __restrict__ ystate, float* __restrict__ zstate,
    int t0, int Tcc)
{
  extern __shared__ char lds_raw[];
  float* G   = (float*)lds_raw;               // [16][1028] fp32
  u16* ypre  = (u16*)(lds_raw + 65792);       // 4096 u16, swizzled granules
  u16* ypost = ypre + 4096;
  u16* zbf   = ypost + 4096;
  float* sc  = (float*)(zbf + 4096);          // 48 floats

  const int Wg = blockIdx.x;
  const int tid = threadIdx.x;
  const int l = tid & 63;
  const int wv = tid >> 6;
  const int row = tid >> 5;                   // phase-B row 0..15
  const int k0 = (tid & 31) * 8;              // phase-B col base

  // ---- persistent registers ----
  float zc[8];                                // z carry (row, k0+j)
  float yc[2][4];                             // y carry (tz_, r)
  float biasA0[8], biasAn[8], bzl[2];

  // init
  {
#pragma unroll
    for (int j = 0; j < 8; ++j) {
      int to = wv + 8 * j;
      int n = (to << 4) | (l & 15);
      biasA0[j] = biasD0[n];
      biasAn[j] = biasDn[n];
    }
#pragma unroll
    for (int tz_ = 0; tz_ < 2; ++tz_) bzl[tz_] = b_z[((2 * wv + tz_) << 4) | (l & 15)];
    if (t0 == 0) {
#pragma unroll
      for (int j = 0; j < 8; ++j) zc[j] = 0.f;
#pragma unroll
      for (int tz_ = 0; tz_ < 2; ++tz_)
#pragma unroll
        for (int r = 0; r < 4; ++r) yc[tz_][r] = 0.f;
#pragma unroll
      for (int j = 0; j < 8; ++j) {
        int k = k0 + j;
        int ls = (((k & 15) >> 2) << 4) | row;
        int e = (k & 3) | (((k >> 4) & 1) << 2);
        ypost[(k >> 5) * 512 + gsw(ls) * 8 + e] = 0;
      }
    } else {
#pragma unroll
      for (int j = 0; j < 8; ++j) zc[j] = zstate[(size_t)(Wg * 16 + row) * 256 + k0 + j];
#pragma unroll
      for (int tz_ = 0; tz_ < 2; ++tz_) {
        int n = ((2 * wv + tz_) << 4) | (l & 15);
#pragma unroll
        for (int r = 0; r < 4; ++r)
          yc[tz_][r] = ystate[(size_t)(Wg * 16 + 4 * (l >> 4) + r) * 256 + n];
      }
#pragma unroll
      for (int j = 0; j < 8; ++j) {
        int k = k0 + j;
        float yv = ystate[(size_t)(Wg * 16 + row) * 256 + k];
        int ls = (((k & 15) >> 2) << 4) | row;
        int e = (k & 3) | (((k >> 4) & 1) << 2);
        ypost[(k >> 5) * 512 + gsw(ls) * 8 + e] = f2bf(yv);
      }
    }
  }
  __syncthreads();

  float wdt0 = W_dt[0], wdt1 = W_dt[1], bdt0 = b_dt[0], bdt1 = b_dt[1];

  for (int tl = 0; tl < Tcc; ++tl) {
    int t = t0 + tl;
    if (tid < 16) {
      float dl = dt[(size_t)t * 256 + Wg * 16 + tid] / 10.0f;
      sc[tid] = dl;
      sc[16 + tid] = sigm(fmaf(dl, wdt0, bdt0));   // -> ms_dt_bar (y gate)
      sc[32 + tid] = sigm(fmaf(dl, wdt1, bdt1));   // -> ms_dt (z gate)
    }
    for (int d = 0; d < 10; ++d) {
      int step = tl * 10 + d;
      // ---- prefetch noise (consumed in B and C) ----
      uint4 snz = *reinterpret_cast<const uint4*>(Snz + (((size_t)step * 16 + Wg) * 512 + tid) * 8);
      uint4 sny = *reinterpret_cast<const uint4*>(Sny + (((size_t)step * 16 + Wg) * 512 + tid) * 8);

      // ---- Phase A: merged ti + th, acc-fused ----
      {
        bf16x8_t a1[8], ag[8];
        if (d == 0) {
          const u16* ap = inpPack + (size_t)(tl * 16 + Wg) * 4096 + (size_t)l * 8;
#pragma unroll
          for (int kk = 0; kk < 8; ++kk) a1[kk] = *reinterpret_cast<const bf16x8_t*>(ap + kk * 512);
        } else {
#pragma unroll
          for (int kk = 0; kk < 8; ++kk)
            a1[kk] = *reinterpret_cast<const bf16x8_t*>(ypre + kk * 512 + gsw(l) * 8);
        }
#pragma unroll
        for (int kk = 0; kk < 8; ++kk)
          ag[kk] = *reinterpret_cast<const bf16x8_t*>(ypost + kk * 512 + gsw(l) * 8);
        const u16* BW = (d == 0) ? Wipack : Epack;
#pragma unroll 2
        for (int j = 0; j < 8; ++j) {
          int to = wv + 8 * j;
          const u16* bp = BW + (size_t)to * 4096 + (size_t)l * 8;
          f32x4_t acc = {0.f, 0.f, 0.f, 0.f};
#pragma unroll
          for (int kk = 0; kk < 8; ++kk)
            acc = mfma16(a1[kk], *reinterpret_cast<const bf16x8_t*>(bp + kk * 512), acc);
          if (to < 32 || to >= 48) {
            int toh = (to < 32) ? (64 + to) : (48 + to);
            const u16* hp = Epack + (size_t)toh * 4096 + (size_t)l * 8;
#pragma unroll
            for (int kk = 0; kk < 8; ++kk)
              acc = mfma16(ag[kk], *reinterpret_cast<const bf16x8_t*>(hp + kk * 512), acc);
          }
          float bv = (d == 0) ? biasA0[j] : biasAn[j];
          int n = (to << 4) | (l & 15);
#pragma unroll
          for (int r = 0; r < 4; ++r)
            G[(4 * (l >> 4) + r) * 1028 + n] = acc[r] + bv;
        }
      }
      __syncthreads();

      // ---- Phase B: z update (carry in regs), write zbf frags ----
      {
        float dl = sc[row], s2v = sc[32 + row];
        f32x4_t p2a = *(const f32x4_t*)&G[row * 1028 + 256 + k0];
        f32x4_t p2b = *(const f32x4_t*)&G[row * 1028 + 256 + k0 + 4];
        f32x4_t iya = *(const f32x4_t*)&G[row * 1028 + 768 + k0];
        f32x4_t iyb = *(const f32x4_t*)&G[row * 1028 + 768 + k0 + 4];
        const u16* nzp = (const u16*)&snz;
        union { u16 h[4]; uint2 v; } zlo, zhi;
#pragma unroll
        for (int j = 0; j < 4; ++j) {
          float ms = s2v * sigm(p2a[j]);
          float zn = (1.0f - ms) * zc[j] + ms * tanh_f(iya[j]);
          zlo.h[j] = f2bf(zn);
          zc[j] = fmaf(bf2f(nzp[j]), dl, zn);
        }
#pragma unroll
        for (int j = 0; j < 4; ++j) {
          float ms = s2v * sigm(p2b[j]);
          float zn = (1.0f - ms) * zc[4 + j] + ms * tanh_f(iyb[j]);
          zhi.h[j] = f2bf(zn);
          zc[4 + j] = fmaf(bf2f(nzp[4 + j]), dl, zn);
        }
        int kk = k0 >> 5;
        int e0 = ((k0 >> 4) & 1) << 2;
        int ls0 = (((k0) & 15) >> 2 << 4) | row;
        int ls1 = (((k0 + 4) & 15) >> 2 << 4) | row;
        *reinterpret_cast<uint2*>(&zbf[kk * 512 + gsw(ls0) * 8 + e0]) = zlo.v;
        *reinterpret_cast<uint2*>(&zbf[kk * 512 + gsw(ls1) * 8 + e0]) = zhi.v;
      }
      __syncthreads();

      // ---- Phase C: W_z MFMA + y update ----
      {
        bf16x8_t wzf[2][8];
#pragma unroll
        for (int tz_ = 0; tz_ < 2; ++tz_)
#pragma unroll
          for (int kk = 0; kk < 8; ++kk)
            wzf[tz_][kk] = *reinterpret_cast<const bf16x8_t*>(
                Wzpack + (size_t)(2 * wv + tz_) * 4096 + (size_t)kk * 512 + (size_t)l * 8);
        bf16x8_t zfr[8];
#pragma unroll
        for (int kk = 0; kk < 8; ++kk)
          zfr[kk] = *reinterpret_cast<const bf16x8_t*>(zbf + kk * 512 + gsw(l) * 8);
        f32x4_t uacc[2];
#pragma unroll
        for (int tz_ = 0; tz_ < 2; ++tz_) {
          f32x4_t acc = {0.f, 0.f, 0.f, 0.f};
#pragma unroll
          for (int kk = 0; kk < 8; ++kk) acc = mfma16(zfr[kk], wzf[tz_][kk], acc);
          uacc[tz_] = acc;
        }
        const u16* nyp = (const u16*)&sny;
#pragma unroll
        for (int tz_ = 0; tz_ < 2; ++tz_) {
          int n = ((2 * wv + tz_) << 4) | (l & 15);
#pragma unroll
          for (int r = 0; r < 4; ++r) {
            int m2 = 4 * (l >> 4) + r;
            float u = uacc[tz_][r] + bzl[tz_] + G[m2 * 1028 + 512 + n];
            float msb = sc[16 + m2] * sigm(G[m2 * 1028 + n]);
            float yn = (1.0f - msb) * yc[tz_][r] + msb * tanh_f(u);
            float ypn = fmaf(bf2f(nyp[(tz_ << 2) | r]), sc[m2], yn);
            yc[tz_][r] = ypn;
            int kky = n >> 5;
            int lsy = (((n & 15) >> 2) << 4) | m2;
            int ey = (n & 3) | (((n >> 4) & 1) << 2);
            int off = kky * 512 + gsw(lsy) * 8 + ey;
            ypre[off] = f2bf(yn);
            ypost[off] = f2bf(ypn);
            if (d == 9)
              Ypack[(size_t)(tl * 16 + Wg) * 4096 + kky * 512 + lsy * 8 + ey] = f2bf(ypn);
          }
        }
      }
      __syncthreads();
    }
  }
  // ---- store carries ----
#pragma unroll
  for (int j = 0; j < 8; ++j) zstate[(size_t)(Wg * 16 + row) * 256 + k0 + j] = zc[j];
#pragma unroll
  for (int tz_ = 0; tz_ < 2; ++tz_) {
    int n = ((2 * wv + tz_) << 4) | (l & 15);
#pragma unroll
    for (int r = 0; r < 4; ++r)
      ystate[(size_t)(Wg * 16 + 4 * (l >> 4) + r) * 256 + n] = yc[tz_][r];
  }
}

// out[t] = Y[t] @ W_c^T + b_c
__global__ __launch_bounds__(512) void k_out(const u16* __restrict__ Ypack, const u16* __restrict__ Wcpack,
                                             const float* __restrict__ b_c, float* __restrict__ out, int t0) {
  int tl = blockIdx.x; int mh = blockIdx.y;
  int l = threadIdx.x & 63; int wv = threadIdx.x >> 6;
  int mt = mh * 8 + wv;
  const u16* Ab = Ypack + (size_t)(tl * 16 + mt) * 4096 + (size_t)l * 8;
  bf16x8_t af[8];
#pragma unroll
  for (int kk = 0; kk < 8; ++kk) af[kk] = *reinterpret_cast<const bf16x8_t*>(Ab + kk * 512);
#pragma unroll 1
  for (int nt = 0; nt < 16; ++nt) {
    f32x4_t acc = {0.f, 0.f, 0.f, 0.f};
    const u16* bp = Wcpack + ((size_t)nt * 8 * 64 + l) * 8;
#pragma unroll
    for (int kk = 0; kk < 8; ++kk) {
      bf16x8_t bfr = *reinterpret_cast<const bf16x8_t*>(bp + kk * 512);
      acc = mfma16(af[kk], bfr, acc);
    }
    int n = (nt << 4) | (l & 15);
    float bc = b_c[n];
#pragma unroll
    for (int r = 0; r < 4; ++r) {
      int m = (mt << 4) + ((l >> 4) << 2) + r;
      out[((size_t)(t0 + tl) * 256 + m) * 256 + n] = acc[r] + bc;
    }
  }
}

// ---------------------------------------------------------------------------
extern "C" void kernel_launch(void* const* d_in, const int* in_sizes, int n_in,
                              void* d_out, int out_size, void* d_ws, size_t ws_size,
                              hipStream_t stream) {
  const float* input = (const float*)d_in[0];
  const float* dt    = (const float*)d_in[1];
  const float* W_i   = (const float*)d_in[2];
  const float* b_i   = (const float*)d_in[3];
  const float* W_h   = (const float*)d_in[4];
  const float* b_h   = (const float*)d_in[5];
  const float* W_z   = (const float*)d_in[6];
  const float* b_z   = (const float*)d_in[7];
  const float* W_dt  = (const float*)d_in[8];
  const float* b_dt  = (const float*)d_in[9];
  const float* W_c   = (const float*)d_in[10];
  const float* b_c   = (const float*)d_in[11];
  const float* W_s   = (const float*)d_in[12];
  const float* b_s   = (const float*)d_in[13];
  float* out = (float*)d_out;

  char* ws = (char*)d_ws;
  size_t off = 0;
  auto alloc = [&](size_t bytes) -> char* {
    char* p = ws + off; off = (off + bytes + 255) & ~(size_t)255; return p;
  };
  u16* Epack   = (u16*)alloc((size_t)112 * 8 * 512 * 2);   // [Wic;Wh] 1792x256
  u16* Wipack  = (u16*)alloc((size_t)64 * 8 * 512 * 2);
  u16* Wzpack  = (u16*)alloc((size_t)16 * 8 * 512 * 2);
  u16* Wcpack  = (u16*)alloc((size_t)16 * 8 * 512 * 2);
  u16* Wspack  = (u16*)alloc((size_t)32 * 16 * 512 * 2);
  float* bip   = (float*)alloc(1024 * 4);
  float* biasD0= (float*)alloc(1024 * 4);
  float* biasDn= (float*)alloc(1024 * 4);
  float* Wic   = (float*)alloc((size_t)1024 * 256 * 4);
  float* ystate= (float*)alloc((size_t)256 * 256 * 4);
  float* zstate= (float*)alloc((size_t)256 * 256 * 4);
  size_t fixed = off;
  size_t per_t = (size_t)10 * 131072 * 2      // Apack
               + (size_t)10 * 65536 * 2 * 2   // Sny + Snz
               + (size_t)16 * 8 * 512 * 2 + (size_t)16 * 8 * 512 * 2  // inpPack + Ypack
               + 4 * 256;
  int Tc = 1;
  if (ws_size > fixed + per_t) {
    size_t n = (ws_size - fixed) / per_t;
    Tc = (n > 128) ? 128 : (int)n;
  }
  if (Tc < 1) Tc = 1;
  u16* Apack   = (u16*)alloc((size_t)Tc * 10 * 131072 * 2);
  u16* Sny     = (u16*)alloc((size_t)Tc * 10 * 65536 * 2);
  u16* Snz     = (u16*)alloc((size_t)Tc * 10 * 65536 * 2);
  u16* inpPack = (u16*)alloc((size_t)Tc * 16 * 8 * 512 * 2);
  u16* Ypack   = (u16*)alloc((size_t)Tc * 16 * 8 * 512 * 2);

  hipFuncSetAttribute((const void*)k_recur, hipFuncAttributeMaxDynamicSharedMemorySize, R_LDS_BYTES);

  k_prep<<<1024, 256, 0, stream>>>(W_i, W_c, b_i, b_c, Wic, bip);
  k_bias<<<4, 256, 0, stream>>>(b_i, bip, b_h, biasD0, biasDn);
  k_packw<<<(112 * 8 * 64) / 256, 256, 0, stream>>>(Wic, 1024, W_h, Epack, 1792, 256);
  k_packw<<<(64 * 8 * 64) / 256, 256, 0, stream>>>(W_i, 1024, (const float*)nullptr, Wipack, 1024, 256);
  k_packw<<<(16 * 8 * 64) / 256, 256, 0, stream>>>(W_z, 256, (const float*)nullptr, Wzpack, 256, 256);
  k_packw<<<(16 * 8 * 64) / 256, 256, 0, stream>>>(W_c, 256, (const float*)nullptr, Wcpack, 256, 256);
  k_packw<<<(32 * 16 * 64) / 256, 256, 0, stream>>>(W_s, 512, (const float*)nullptr, Wspack, 512, 512);

  for (int t0 = 0; t0 < 128; t0 += Tc) {
    int Tcc = (128 - t0 < Tc) ? (128 - t0) : Tc;
    int nsteps = Tcc * 10;
    k_gen<<<nsteps * 128, 1024, 0, stream>>>(Apack, t0 * 10);
    dim3 g2(nsteps, 4);
    k_sgemm<<<g2, 512, 0, stream>>>(Apack, Wspack, b_s, Sny, Snz);
    int totalA = Tcc * 16 * 8 * 64;
    k_packa<<<(totalA + 255) / 256, 256, 0, stream>>>(input, t0, Tcc, inpPack);
    k_recur<<<16, 512, R_LDS_BYTES, stream>>>(dt, Epack, Wipack, Wzpack, biasD0, biasDn,
                                              b_z, W_dt, b_dt, inpPack, Sny, Snz,
                                              Ypack, ystate, zstate, t0, Tcc);
    dim3 ge(Tcc, 2);
    k_out<<<ge, 512, 0, stream>>>(Ypack, Wcpack, b_c, out, t0);
  }
}